// Round 11
// baseline (57.883 us; speedup 1.0000x reference)
//
#include <hip/hip_runtime.h>

typedef unsigned short u16;
typedef unsigned int u32;
typedef float f32x4 __attribute__((ext_vector_type(4)));
typedef short s16x8 __attribute__((ext_vector_type(8)));

#define MFMA_BF16(a, b, c) __builtin_amdgcn_mfma_f32_16x16x32_bf16((a), (b), (c), 0, 0, 0)

// Problem constants: B=8, T=2048, D=1024, HS=64; scale = 1/sqrt(2048) (per reference!)

__device__ __forceinline__ u16 f2bf(float f) {
  union { float f; u32 u; } v; v.f = f;
  u32 u = v.u;
  return (u16)((u + 0x7FFFu + ((u >> 16) & 1u)) >> 16);  // RNE f32->bf16
}
__device__ __forceinline__ u16 f2bf_t(float f) {  // truncating f32->bf16 (P tile only)
  union { float f; u32 u; } v; v.f = f;
  return (u16)(v.u >> 16);
}
__device__ __forceinline__ s16x8 pack_bf8(float4 a, float4 b) {
  union { u32 d[4]; s16x8 v; } u;
  u.d[0] = (u32)f2bf(a.x) | ((u32)f2bf(a.y) << 16);
  u.d[1] = (u32)f2bf(a.z) | ((u32)f2bf(a.w) << 16);
  u.d[2] = (u32)f2bf(b.x) | ((u32)f2bf(b.y) << 16);
  u.d[3] = (u32)f2bf(b.z) | ((u32)f2bf(b.w) << 16);
  return u.v;
}
__device__ __forceinline__ void gload_lds16(const void* g, void* l) {
  __builtin_amdgcn_global_load_lds((const __attribute__((address_space(1))) u32*)g,
                                   (__attribute__((address_space(3))) u32*)l, 16, 0, 0);
}

// ---- Kernel 1: W [1024][64] f32 x3 -> Wt3 bf16 [16 kstep][192 row][64 k]
// (rows: q 0-63, k 64-127, v 128-191). Each k-step's W = one contiguous 24KB chunk.
__global__ __launch_bounds__(256) void wt_convert(const float* __restrict__ Wq,
                                                  const float* __restrict__ Wk,
                                                  const float* __restrict__ Wv,
                                                  u16* __restrict__ Wt3) {
  __shared__ u16 Ls[64][70];
  const int bid = blockIdx.x;
  const int m = bid >> 4, kstep = bid & 15, d0 = kstep * 64;
  const float* W = (m == 0) ? Wq : (m == 1) ? Wk : Wv;
  const int t = threadIdx.x;
  {
    const int dr = t >> 2, hc = (t & 3) * 16;
    const float4* src = (const float4*)(W + (size_t)(d0 + dr) * 64 + hc);
    float4 f0 = src[0], f1 = src[1], f2 = src[2], f3 = src[3];
    float fl[16] = {f0.x, f0.y, f0.z, f0.w, f1.x, f1.y, f1.z, f1.w,
                    f2.x, f2.y, f2.z, f2.w, f3.x, f3.y, f3.z, f3.w};
#pragma unroll
    for (int j = 0; j < 8; ++j) {
      u32 pk = (u32)f2bf(fl[2 * j]) | ((u32)f2bf(fl[2 * j + 1]) << 16);
      *(u32*)&Ls[dr][hc + 2 * j] = pk;
    }
  }
  __syncthreads();
  {
    const int h = t >> 2, dcs = (t & 3) * 16;
    const int grow = m * 64 + h;
    u32 po[8];
#pragma unroll
    for (int j = 0; j < 8; ++j)
      po[j] = (u32)Ls[dcs + 2 * j][h] | ((u32)Ls[dcs + 2 * j + 1][h] << 16);
    u16* dst = Wt3 + (size_t)kstep * 12288 + grow * 64 + dcs;
    *(uint4*)&dst[0] = make_uint4(po[0], po[1], po[2], po[3]);
    *(uint4*)&dst[8] = make_uint4(po[4], po[5], po[6], po[7]);
  }
}

// ---- Kernel 2: QKV projection. C[16384,192] = X[16384,1024] @ W[1024,192], bf16 MFMA.
// m97-proven shape: simple 2-barrier double-buffered loop + global_load_lds staging,
// sized for 2 BLOCKS/CU so inter-block overlap hides the barrier's vmcnt(0) drain
// (rounds 8-10 ran 1 block/CU -> nothing could overlap the drain; this was the bug).
// BM=32, BN=192, BK=64, 512 thr (8 waves), grid 512. Wave (msub=w&1, ntg=w>>1):
// 16 rows x 3 n-tiles, 6 MFMA/step, acc[3]. X staged as f32 (pack at A-read).
// Swizzles (verified 0-conflict in r9): X g16^=(row&15), W g8^=(row&7), both-sides.
__global__ __launch_bounds__(512) void qkv_gemm(const float* __restrict__ x,
                                                const u16* __restrict__ Wt3,
                                                u16* __restrict__ qo,
                                                u16* __restrict__ ko,
                                                u16* __restrict__ vTo) {
  __shared__ float Xf[2][2048];  // [32 row][64 f32] 8KB/buf, swizzled
  __shared__ u16 Wl[2][12288];   // [192 row][64 bf16] 24KB/buf, swizzled
  const int tid = threadIdx.x, lane = tid & 63, w = tid >> 6;
  const int lc = lane & 15, hi = lane >> 4;
  const int m0 = blockIdx.x * 32;
  const int msub = w & 1, ntg = w >> 1;

  f32x4 acc[3];
#pragma unroll
  for (int i = 0; i < 3; ++i) acc[i] = (f32x4){0.f, 0.f, 0.f, 0.f};

  // X staging: wave w stages rows 4w..4w+3. lane l -> row 4w+(l>>4), dest granule
  // l&15; source granule = (l&15)^(row&15).
  const int rX = w * 4 + (lane >> 4);
  const int gXs = (lane & 15) ^ (rX & 15);
  const float* xsrc = x + (size_t)(m0 + rX) * 1024 + gXs * 4;
  // W staging: 24 chunks of 1KB; wave w issues chunks i=3w..3w+2. Chunk i covers
  // rows 8i..8i+7; lane l -> row 8i+(l>>3), dest granule l&7, src g=(l&7)^((l>>3)&7).
  const int wr_r = lane >> 3;
  const int wr_g = (lane & 7) ^ ((lane >> 3) & 7);

  auto stage = [&](int t, int bf) {
    gload_lds16(xsrc + t * 64, &Xf[bf][w * 256]);
#pragma unroll
    for (int c = 0; c < 3; ++c) {
      const int i = w * 3 + c;
      gload_lds16(Wt3 + (size_t)t * 12288 + (i * 8 + wr_r) * 64 + wr_g * 8,
                  &Wl[bf][i * 512]);
    }
  };

  // swizzled read offsets (element units)
  const int rA = msub * 16 + lc;
  int aof[2][2];
#pragma unroll
  for (int ks = 0; ks < 2; ++ks) {
    const int g0 = ks * 8 + hi * 2;
    aof[ks][0] = rA * 64 + ((g0 ^ (rA & 15)) << 2);
    aof[ks][1] = rA * 64 + (((g0 + 1) ^ (rA & 15)) << 2);
  }
  int bof[2][3];
#pragma unroll
  for (int ks = 0; ks < 2; ++ks)
#pragma unroll
    for (int j = 0; j < 3; ++j) {
      const int rB = (ntg * 3 + j) * 16 + lc;
      bof[ks][j] = rB * 64 + (((ks * 4 + hi) ^ (rB & 7)) << 3);
    }

  stage(0, 0);
  __syncthreads();
  int buf = 0;

  for (int t = 0; t < 16; ++t) {
    if (t < 15) stage(t + 1, buf ^ 1);
#pragma unroll
    for (int ks = 0; ks < 2; ++ks) {
      float4 alo = *(const float4*)&Xf[buf][aof[ks][0]];
      float4 ahi = *(const float4*)&Xf[buf][aof[ks][1]];
      s16x8 a = pack_bf8(alo, ahi);
#pragma unroll
      for (int j = 0; j < 3; ++j) {
        s16x8 bfr = *(const s16x8*)&Wl[buf][bof[ks][j]];
        acc[j] = MFMA_BF16(a, bfr, acc[j]);
      }
    }
    if (t < 15) {
      __syncthreads();
      buf ^= 1;
    }
  }

  // epilogue: C layout col=lane&15, row=(lane>>4)*4+r
#pragma unroll
  for (int j = 0; j < 3; ++j) {
    const int nt = ntg * 3 + j;
#pragma unroll
    for (int r = 0; r < 4; ++r) {
      const int gr = m0 + msub * 16 + hi * 4 + r;
      const u16 val = f2bf(acc[j][r]);
      const int n = nt * 16 + lc;
      if (nt < 4) {
        qo[gr * 64 + n] = val;
      } else if (nt < 8) {
        ko[gr * 64 + (n - 64)] = val;
      } else {
        int b = gr >> 11, t2 = gr & 2047;
        vTo[((b << 6) + (n - 128)) * 2048 + t2] = val;
      }
    }
  }
}

// ---- Kernel 3: causal flash attention, no-max softmax. 256 threads = 4 waves.
// (unchanged from round 5/7: ~10us)
__global__ __launch_bounds__(256, 2) void attn_fwd(const u16* __restrict__ qb,
                                                   const u16* __restrict__ kb,
                                                   const u16* __restrict__ vT,
                                                   float* __restrict__ out) {
  __shared__ float PoS[4][32][66];  // per-wave merge buffer; P tile [32][40]u16 unioned in
  __shared__ float Pl[4][32];       // per-wave denominator partials
  const int tid = threadIdx.x, lane = tid & 63, w = tid >> 6;
  const int lc = lane & 15, hi = lane >> 4;
  const int bid = blockIdx.x;
  const int b = bid & 7, v = 63 - (bid >> 3);  // batch, q-tile id (heavy-first)
  const int q0 = v * 32;                       // q-tile base row within batch
  const int brow = b * 2048;
  u16* Pw = (u16*)&PoS[w][0][0];  // [32][40] u16 view, per-wave

  s16x8 aq[2][2];
#pragma unroll
  for (int sub = 0; sub < 2; ++sub) {
    const u16* qrow = qb + (size_t)(brow + q0 + sub * 16 + lc) * 64;
    aq[sub][0] = *(const s16x8*)(qrow + hi * 8);
    aq[sub][1] = *(const s16x8*)(qrow + 32 + hi * 8);
  }

  f32x4 o[2][4];
  float lrow[2][4];
#pragma unroll
  for (int sub = 0; sub < 2; ++sub)
#pragma unroll
    for (int i = 0; i < 4; ++i) {
      o[sub][i] = (f32x4){0.f, 0.f, 0.f, 0.f};
      lrow[sub][i] = 0.f;
    }

  const float SL = 0.031879357f;  // (1/sqrt(2048)) * log2(e)
  const int nk = v + 1;           // causal kv-tiles of 32 for this q-tile
  const int c = (nk + 3) >> 2;    // chunk per split-wave (4-way)
  const int s = w;
  const int it0 = s * c;
  const int it1 = min(it0 + c, nk);

  const u16* kbase = kb + (size_t)brow * 64;

  for (int it = it0; it < it1; ++it) {
    const int kvb = it * 32;
    const u16* krow0 = kbase + (size_t)(kvb + lc) * 64;
    const u16* krow1 = kbase + (size_t)(kvb + 16 + lc) * 64;
    s16x8 k00 = *(const s16x8*)(krow0 + hi * 8);
    s16x8 k01 = *(const s16x8*)(krow0 + 32 + hi * 8);
    s16x8 k10 = *(const s16x8*)(krow1 + hi * 8);
    s16x8 k11 = *(const s16x8*)(krow1 + 32 + hi * 8);
    s16x8 bv[4];
#pragma unroll
    for (int nt = 0; nt < 4; ++nt)
      bv[nt] = *(const s16x8*)&vT[(size_t)(b * 64 + nt * 16 + lc) * 2048 + kvb + hi * 8];

    f32x4 sc[2][2];
#pragma unroll
    for (int sub = 0; sub < 2; ++sub) {
      sc[sub][0] = (f32x4){0.f, 0.f, 0.f, 0.f};
      sc[sub][1] = (f32x4){0.f, 0.f, 0.f, 0.f};
      sc[sub][0] = MFMA_BF16(aq[sub][0], k00, sc[sub][0]);
      sc[sub][0] = MFMA_BF16(aq[sub][1], k01, sc[sub][0]);
      sc[sub][1] = MFMA_BF16(aq[sub][0], k10, sc[sub][1]);
      sc[sub][1] = MFMA_BF16(aq[sub][1], k11, sc[sub][1]);
    }

    if (kvb + 31 <= q0) {  // tile fully below diagonal: no masks
#pragma unroll
      for (int sub = 0; sub < 2; ++sub)
#pragma unroll
        for (int r = 0; r < 4; ++r) {
          float p0 = exp2f(sc[sub][0][r] * SL);
          float p1 = exp2f(sc[sub][1][r] * SL);
          lrow[sub][r] += p0 + p1;
          Pw[(sub * 16 + hi * 4 + r) * 40 + lc] = f2bf_t(p0);
          Pw[(sub * 16 + hi * 4 + r) * 40 + 16 + lc] = f2bf_t(p1);
        }
    } else {  // diagonal tile: causal masks
#pragma unroll
      for (int sub = 0; sub < 2; ++sub)
#pragma unroll
        for (int r = 0; r < 4; ++r) {
          const int qt = q0 + sub * 16 + hi * 4 + r;
          const int kv0 = kvb + lc;
          float p0 = (kv0 <= qt) ? exp2f(sc[sub][0][r] * SL) : 0.f;
          float p1 = (kv0 + 16 <= qt) ? exp2f(sc[sub][1][r] * SL) : 0.f;
          lrow[sub][r] += p0 + p1;
          Pw[(sub * 16 + hi * 4 + r) * 40 + lc] = f2bf_t(p0);
          Pw[(sub * 16 + hi * 4 + r) * 40 + 16 + lc] = f2bf_t(p1);
        }
    }
    asm volatile("s_waitcnt lgkmcnt(0)" ::: "memory");
    s16x8 pa0 = *(const s16x8*)&Pw[lc * 40 + hi * 8];
    s16x8 pa1 = *(const s16x8*)&Pw[(16 + lc) * 40 + hi * 8];
#pragma unroll
    for (int nt = 0; nt < 4; ++nt) {
      o[0][nt] = MFMA_BF16(pa0, bv[nt], o[0][nt]);
      o[1][nt] = MFMA_BF16(pa1, bv[nt], o[1][nt]);
    }
  }

#pragma unroll
  for (int sub = 0; sub < 2; ++sub)
#pragma unroll
    for (int r = 0; r < 4; ++r) {
      float l = lrow[sub][r];
      l += __shfl_xor(l, 1);
      l += __shfl_xor(l, 2);
      l += __shfl_xor(l, 4);
      l += __shfl_xor(l, 8);
      lrow[sub][r] = l;
    }

  if (lc == 0) {
#pragma unroll
    for (int sub = 0; sub < 2; ++sub)
#pragma unroll
      for (int r = 0; r < 4; ++r) Pl[w][sub * 16 + hi * 4 + r] = lrow[sub][r];
  }
  float* Pow = &PoS[w][0][0];
#pragma unroll
  for (int sub = 0; sub < 2; ++sub)
#pragma unroll
    for (int nt = 0; nt < 4; ++nt)
#pragma unroll
      for (int r = 0; r < 4; ++r)
        Pow[(sub * 16 + hi * 4 + r) * 66 + nt * 16 + lc] = o[sub][nt][r];
  __syncthreads();

#pragma unroll
  for (int rr = 0; rr < 8; ++rr) {
    const int row = w * 8 + rr;
    float L = Pl[0][row] + Pl[1][row] + Pl[2][row] + Pl[3][row];
    float val = PoS[0][row][lane] + PoS[1][row][lane] + PoS[2][row][lane] + PoS[3][row][lane];
    out[(size_t)(brow + q0 + row) * 64 + lane] = val / L;
  }
}

extern "C" void kernel_launch(void* const* d_in, const int* in_sizes, int n_in,
                              void* d_out, int out_size, void* d_ws, size_t ws_size,
                              hipStream_t stream) {
  (void)in_sizes; (void)n_in; (void)out_size; (void)ws_size;
  const float* x = (const float*)d_in[0];
  const float* Wq = (const float*)d_in[1];
  const float* Wk = (const float*)d_in[2];
  const float* Wv = (const float*)d_in[3];
  float* out = (float*)d_out;

  u16* wsu = (u16*)d_ws;
  u16* Wt = wsu;                      // 16*192*64 = 196608 (k-step-major layout)
  u16* qb = Wt + 192 * 1024;          // 8*2048*64
  u16* kb = qb + 8 * 2048 * 64;       // 8*2048*64
  u16* vT = kb + 8 * 2048 * 64;       // 8*64*2048
  // total ws use: 6,684,672 bytes

  wt_convert<<<48, 256, 0, stream>>>(Wq, Wk, Wv, Wt);
  qkv_gemm<<<512, 512, 0, stream>>>(x, Wt, qb, kb, vT);
  attn_fwd<<<512, 256, 0, stream>>>(qb, kb, vT, out);
}